// Round 1
// baseline (56.416 us; speedup 1.0000x reference)
//
#include <hip/hip_runtime.h>
#include <stdint.h>

#define TT 128
#define HH 256
#define WW 256
#define CC 3
#define PLANE (TT*HH*WW)            // 8388608 elements per channel
#define FRAME (HH*WW)               // 65536 pixels per frame
#define WPR   (WW/64)               // 4 u64 words per row
#define FRAME_WORDS (HH*WPR)        // 1024 words per frame
#define TOTAL_WORDS (TT*FRAME_WORDS)// 131072 words (1 MiB)

// Kernel 1: per-pixel mask, bit-packed via wave64 ballot.
__global__ __launch_bounds__(256) void mask_kernel(const float* __restrict__ X,
                                                   const float* __restrict__ bg,
                                                   uint64_t* __restrict__ mw) {
    int p = blockIdx.x * blockDim.x + threadIdx.x;   // pixel index in [0, T*H*W)
    int hw = p & (FRAME - 1);                        // pixel within frame
    float x0 = X[p];
    float x1 = X[PLANE + p];
    float x2 = X[2 * PLANE + p];
    const float* b = bg + hw * 3;
    float d0 = fabsf(x0 - b[0]);
    float d1 = fabsf(x1 - b[1]);
    float d2 = fabsf(x2 - b[2]);
    float s = (d0 + d1) + d2;                        // same order as np pairwise for n=3
    uint64_t bal = __ballot(s > 0.5f);
    if ((threadIdx.x & 63) == 0) mw[p >> 6] = bal;
}

// Kernel 2: 5 iterations of cross (4-connected) dilation on bit-packed frames.
// One block per frame; one thread per row; row = 4 x u64 in registers + LDS.
__global__ __launch_bounds__(256) void dilate_kernel(const uint64_t* __restrict__ in,
                                                     uint64_t* __restrict__ out) {
    __shared__ uint64_t buf[HH][WPR];               // 8 KiB
    const int t = blockIdx.x;
    const int h = threadIdx.x;
    const uint64_t* fin = in + (size_t)t * FRAME_WORDS;
    uint64_t r[WPR];
#pragma unroll
    for (int i = 0; i < WPR; ++i) { r[i] = fin[h * WPR + i]; buf[h][i] = r[i]; }
    __syncthreads();
#pragma unroll
    for (int it = 0; it < 5; ++it) {
        uint64_t nr[WPR];
#pragma unroll
        for (int i = 0; i < WPR; ++i) {
            uint64_t c = r[i];
            uint64_t lf = (c << 1) | (i > 0      ? (r[i - 1] >> 63) : 0ULL);
            uint64_t rt = (c >> 1) | (i < WPR-1  ? (r[i + 1] << 63) : 0ULL);
            uint64_t up = (h > 0)      ? buf[h - 1][i] : 0ULL;
            uint64_t dn = (h < HH - 1) ? buf[h + 1][i] : 0ULL;
            nr[i] = c | lf | rt | up | dn;
        }
        __syncthreads();
#pragma unroll
        for (int i = 0; i < WPR; ++i) { r[i] = nr[i]; buf[h][i] = nr[i]; }
        __syncthreads();
    }
    uint64_t* fout = out + (size_t)t * FRAME_WORDS;
#pragma unroll
    for (int i = 0; i < WPR; ++i) fout[h * WPR + i] = r[i];
}

// Kernel 3: out = X * mask, float4 vectorized.
__global__ __launch_bounds__(256) void apply_kernel(const float* __restrict__ X,
                                                    const uint64_t* __restrict__ mw,
                                                    float* __restrict__ out) {
    int gid = blockIdx.x * blockDim.x + threadIdx.x;   // float4 index over [C,T,H,W]
    int e = gid * 4;
    int p = e & (PLANE - 1);                           // pixel index (PLANE = 2^23)
    uint64_t wbits = mw[p >> 6];
    int sh = p & 63;                                   // aligned-4, so sh+3 <= 63
    float4 v = reinterpret_cast<const float4*>(X)[gid];
    v.x *= (float)((wbits >> (sh + 0)) & 1);
    v.y *= (float)((wbits >> (sh + 1)) & 1);
    v.z *= (float)((wbits >> (sh + 2)) & 1);
    v.w *= (float)((wbits >> (sh + 3)) & 1);
    reinterpret_cast<float4*>(out)[gid] = v;
}

extern "C" void kernel_launch(void* const* d_in, const int* in_sizes, int n_in,
                              void* d_out, int out_size, void* d_ws, size_t ws_size,
                              hipStream_t stream) {
    const float* X  = (const float*)d_in[0];
    const float* bg = (const float*)d_in[1];
    float* out = (float*)d_out;
    uint64_t* m0 = (uint64_t*)d_ws;          // raw mask bits   (1 MiB)
    uint64_t* m1 = m0 + TOTAL_WORDS;         // dilated mask    (1 MiB)

    const int pixels = TT * FRAME;           // 8388608
    mask_kernel<<<pixels / 256, 256, 0, stream>>>(X, bg, m0);
    dilate_kernel<<<TT, 256, 0, stream>>>(m0, m1);
    const int nvec4 = (CC * PLANE) / 4;      // 6291456
    apply_kernel<<<nvec4 / 256, 256, 0, stream>>>(X, m1, out);
}

// Round 2
// 40.236 us; speedup vs baseline: 1.4021x; 1.4021x over previous
//
#include <hip/hip_runtime.h>
#include <stdint.h>

#define TT 128
#define HH 256
#define WW 256
#define PLANE (TT*HH*WW)            // 8388608 elems / channel
#define FRAME (HH*WW)               // 65536 px / frame
#define ROWS 32                     // tile rows per block
#define HALO 5
#define BROWS (ROWS + 2*HALO)       // 42 buffered rows
#define THRESH 0.5f

// OR-combine 16 lanes' nibbles into one u64 row-word (all lanes of the
// 16-group end up holding the word). col = 64*(lane>>4) + 4*(lane&15)+p.
__device__ __forceinline__ uint64_t pack16(uint32_t nib) {
    int lane = threadIdx.x & 63;
    uint64_t v = (uint64_t)nib << (4 * (lane & 15));
    v |= __shfl_xor(v, 1);
    v |= __shfl_xor(v, 2);
    v |= __shfl_xor(v, 4);
    v |= __shfl_xor(v, 8);
    return v;
}

// Mask nibble for 4 pixels at (frame t, row gr, cols 4*col4..+3).
// Out-of-frame rows -> 0. Same f32 add order as numpy: (d0+d1)+d2.
__device__ __forceinline__ uint32_t mask_nib(const float* __restrict__ X,
                                             const float* __restrict__ bg,
                                             int t, int gr, int col4) {
    if (gr < 0 || gr >= HH) return 0u;
    size_t pix = (size_t)t * FRAME + (size_t)gr * WW + 4 * col4;
    float4 x0 = *(const float4*)(X + pix);
    float4 x1 = *(const float4*)(X + (size_t)PLANE + pix);
    float4 x2 = *(const float4*)(X + 2 * (size_t)PLANE + pix);
    const float4* bp = (const float4*)(bg + ((size_t)gr * WW + 4 * col4) * 3);
    float4 q0 = bp[0], q1 = bp[1], q2 = bp[2];
    uint32_t nib = 0;
    nib |= ((fabsf(x0.x - q0.x) + fabsf(x1.x - q0.y) + fabsf(x2.x - q0.z)) > THRESH) ? 1u : 0u;
    nib |= ((fabsf(x0.y - q0.w) + fabsf(x1.y - q1.x) + fabsf(x2.y - q1.y)) > THRESH) ? 2u : 0u;
    nib |= ((fabsf(x0.z - q1.z) + fabsf(x1.z - q1.w) + fabsf(x2.z - q2.x)) > THRESH) ? 4u : 0u;
    nib |= ((fabsf(x0.w - q2.y) + fabsf(x1.w - q2.z) + fabsf(x2.w - q2.w)) > THRESH) ? 8u : 0u;
    return nib;
}

__global__ __launch_bounds__(512) void fused_kernel(const float* __restrict__ X,
                                                    const float* __restrict__ bg,
                                                    float* __restrict__ out) {
    __shared__ uint64_t buf[BROWS][4];          // 1344 B
    const int t    = blockIdx.x >> 3;           // frame
    const int j    = blockIdx.x & 7;            // row-tile within frame
    const int r0   = j * ROWS;
    const int tid  = threadIdx.x;
    const int lane = tid & 63;
    const int wave = tid >> 6;                  // 0..7
    const int col4 = lane;                      // float4-column 0..63

    // ---- phase 1: main tile — load X into regs, mask bits into LDS ----
    float4 xv[4][3];
#pragma unroll
    for (int k = 0; k < 4; ++k) {
        const int row = wave + 8 * k;           // tile-local 0..31
        const int gr  = r0 + row;
        size_t pix = (size_t)t * FRAME + (size_t)gr * WW + 4 * col4;
        xv[k][0] = *(const float4*)(X + pix);
        xv[k][1] = *(const float4*)(X + (size_t)PLANE + pix);
        xv[k][2] = *(const float4*)(X + 2 * (size_t)PLANE + pix);
        const float4* bp = (const float4*)(bg + ((size_t)gr * WW + 4 * col4) * 3);
        float4 q0 = bp[0], q1 = bp[1], q2 = bp[2];
        uint32_t nib = 0;
        nib |= ((fabsf(xv[k][0].x - q0.x) + fabsf(xv[k][1].x - q0.y) + fabsf(xv[k][2].x - q0.z)) > THRESH) ? 1u : 0u;
        nib |= ((fabsf(xv[k][0].y - q0.w) + fabsf(xv[k][1].y - q1.x) + fabsf(xv[k][2].y - q1.y)) > THRESH) ? 2u : 0u;
        nib |= ((fabsf(xv[k][0].z - q1.z) + fabsf(xv[k][1].z - q1.w) + fabsf(xv[k][2].z - q2.x)) > THRESH) ? 4u : 0u;
        nib |= ((fabsf(xv[k][0].w - q2.y) + fabsf(xv[k][1].w - q2.z) + fabsf(xv[k][2].w - q2.w)) > THRESH) ? 8u : 0u;
        uint64_t w = pack16(nib);
        if ((lane & 15) == 0) buf[HALO + row][lane >> 4] = w;
    }

    // ---- phase 1b: halo rows (10 of them; slots 0..4 above, 5..9 below) ----
    {   // pass A: slots 0..7 (one wave each)
        const int slot = wave;
        const int gr   = (slot < 5) ? (r0 - HALO + slot) : (r0 + ROWS + (slot - 5));
        const int brow = (slot < 5) ? slot : (HALO + ROWS + (slot - 5));
        uint64_t w = pack16(mask_nib(X, bg, t, gr, col4));
        if ((lane & 15) == 0) buf[brow][lane >> 4] = w;
    }
    if (tid < 128) {  // pass B: slots 8..9 (waves 0..1)
        const int slot = 8 + wave;
        const int gr   = r0 + ROWS + (slot - 5);
        const int brow = HALO + ROWS + (slot - 5);
        uint64_t w = pack16(mask_nib(X, bg, t, gr, col4));
        if ((lane & 15) == 0) buf[brow][lane >> 4] = w;
    }
    __syncthreads();

    // ---- phase 2: 5 cross-dilation iterations on 42x4 u64 words ----
#pragma unroll
    for (int it = 0; it < 5; ++it) {
        uint64_t nv = 0;
        const int b  = tid >> 2;
        const int wi = tid & 3;
        if (tid < BROWS * 4) {
            uint64_t c = buf[b][wi];
            uint64_t l = wi        ? buf[b][wi - 1] : 0ULL;
            uint64_t r = (wi < 3)  ? buf[b][wi + 1] : 0ULL;
            uint64_t u = b         ? buf[b - 1][wi] : 0ULL;
            uint64_t d = (b < BROWS - 1) ? buf[b + 1][wi] : 0ULL;
            nv = c | (c << 1) | (l >> 63) | (c >> 1) | (r << 63) | u | d;
        }
        __syncthreads();
        if (tid < BROWS * 4) buf[b][wi] = nv;
        __syncthreads();
    }

    // ---- phase 3: apply mask to register-held X, store ----
#pragma unroll
    for (int k = 0; k < 4; ++k) {
        const int row = wave + 8 * k;
        const int gr  = r0 + row;
        uint64_t w = buf[HALO + row][col4 >> 4];
        uint32_t nb = (uint32_t)(w >> (4 * (col4 & 15))) & 0xFu;
        float m0 = (float)(nb & 1u);
        float m1 = (float)((nb >> 1) & 1u);
        float m2 = (float)((nb >> 2) & 1u);
        float m3 = (float)((nb >> 3) & 1u);
        size_t pix = (size_t)t * FRAME + (size_t)gr * WW + 4 * col4;
#pragma unroll
        for (int c = 0; c < 3; ++c) {
            float4 v = xv[k][c];
            v.x *= m0; v.y *= m1; v.z *= m2; v.w *= m3;
            *(float4*)(out + (size_t)c * PLANE + pix) = v;
        }
    }
}

extern "C" void kernel_launch(void* const* d_in, const int* in_sizes, int n_in,
                              void* d_out, int out_size, void* d_ws, size_t ws_size,
                              hipStream_t stream) {
    const float* X  = (const float*)d_in[0];
    const float* bg = (const float*)d_in[1];
    float* out = (float*)d_out;
    const int nblocks = TT * (HH / ROWS);   // 128 * 8 = 1024
    fused_kernel<<<nblocks, 512, 0, stream>>>(X, bg, out);
}

// Round 4
// 38.854 us; speedup vs baseline: 1.4520x; 1.0356x over previous
//
#include <hip/hip_runtime.h>
#include <stdint.h>

#define TT 128
#define HH 256
#define WW 256
#define PLANE (TT*HH*WW)            // 8388608 elems / channel
#define FRAME (HH*WW)               // 65536 px / frame
#define ROWS 32                     // tile rows per block
#define HALO 5
#define BROWS (ROWS + 2*HALO)       // 42 buffered rows (fits one wave)
#define THRESH 0.5f

typedef float nfloat4 __attribute__((ext_vector_type(4)));  // native vec for NT store

__device__ __forceinline__ uint64_t shfl64(uint64_t v, int src) {
    uint32_t lo = (uint32_t)v, hi = (uint32_t)(v >> 32);
    lo = __shfl(lo, src);
    hi = __shfl(hi, src);
    return ((uint64_t)hi << 32) | lo;
}

// OR-combine 16 lanes' nibbles into one u64 row-word (all lanes of the
// 16-group end up holding the word). col = 64*(lane>>4) + 4*(lane&15)+p.
__device__ __forceinline__ uint64_t pack16(uint32_t nib) {
    int lane = threadIdx.x & 63;
    uint64_t v = (uint64_t)nib << (4 * (lane & 15));
    v |= __shfl_xor(v, 1);
    v |= __shfl_xor(v, 2);
    v |= __shfl_xor(v, 4);
    v |= __shfl_xor(v, 8);
    return v;
}

// Mask nibble for 4 pixels at (frame t, row gr, cols 4*col4..+3).
// Out-of-frame rows -> 0. Same f32 add order as numpy: (d0+d1)+d2.
__device__ __forceinline__ uint32_t mask_nib(const float* __restrict__ X,
                                             const float* __restrict__ bg,
                                             int t, int gr, int col4) {
    if (gr < 0 || gr >= HH) return 0u;
    size_t pix = (size_t)t * FRAME + (size_t)gr * WW + 4 * col4;
    float4 x0 = *(const float4*)(X + pix);
    float4 x1 = *(const float4*)(X + (size_t)PLANE + pix);
    float4 x2 = *(const float4*)(X + 2 * (size_t)PLANE + pix);
    const float4* bp = (const float4*)(bg + ((size_t)gr * WW + 4 * col4) * 3);
    float4 q0 = bp[0], q1 = bp[1], q2 = bp[2];
    uint32_t nib = 0;
    nib |= ((fabsf(x0.x - q0.x) + fabsf(x1.x - q0.y) + fabsf(x2.x - q0.z)) > THRESH) ? 1u : 0u;
    nib |= ((fabsf(x0.y - q0.w) + fabsf(x1.y - q1.x) + fabsf(x2.y - q1.y)) > THRESH) ? 2u : 0u;
    nib |= ((fabsf(x0.z - q1.z) + fabsf(x1.z - q1.w) + fabsf(x2.z - q2.x)) > THRESH) ? 4u : 0u;
    nib |= ((fabsf(x0.w - q2.y) + fabsf(x1.w - q2.z) + fabsf(x2.w - q2.w)) > THRESH) ? 8u : 0u;
    return nib;
}

__global__ __launch_bounds__(512) void fused_kernel(const float* __restrict__ X,
                                                    const float* __restrict__ bg,
                                                    float* __restrict__ out) {
    __shared__ uint64_t buf[BROWS][4];          // 1344 B
    const int t    = blockIdx.x >> 3;           // frame
    const int j    = blockIdx.x & 7;            // row-tile within frame
    const int r0   = j * ROWS;
    const int tid  = threadIdx.x;
    const int lane = tid & 63;
    const int wave = tid >> 6;                  // 0..7
    const int col4 = lane;                      // float4-column 0..63

    // ---- phase 1: main tile — load X into regs, mask bits into LDS ----
    float4 xv[4][3];
#pragma unroll
    for (int k = 0; k < 4; ++k) {
        const int row = wave + 8 * k;           // tile-local 0..31
        const int gr  = r0 + row;
        size_t pix = (size_t)t * FRAME + (size_t)gr * WW + 4 * col4;
        xv[k][0] = *(const float4*)(X + pix);
        xv[k][1] = *(const float4*)(X + (size_t)PLANE + pix);
        xv[k][2] = *(const float4*)(X + 2 * (size_t)PLANE + pix);
        const float4* bp = (const float4*)(bg + ((size_t)gr * WW + 4 * col4) * 3);
        float4 q0 = bp[0], q1 = bp[1], q2 = bp[2];
        uint32_t nib = 0;
        nib |= ((fabsf(xv[k][0].x - q0.x) + fabsf(xv[k][1].x - q0.y) + fabsf(xv[k][2].x - q0.z)) > THRESH) ? 1u : 0u;
        nib |= ((fabsf(xv[k][0].y - q0.w) + fabsf(xv[k][1].y - q1.x) + fabsf(xv[k][2].y - q1.y)) > THRESH) ? 2u : 0u;
        nib |= ((fabsf(xv[k][0].z - q1.z) + fabsf(xv[k][1].z - q1.w) + fabsf(xv[k][2].z - q2.x)) > THRESH) ? 4u : 0u;
        nib |= ((fabsf(xv[k][0].w - q2.y) + fabsf(xv[k][1].w - q2.z) + fabsf(xv[k][2].w - q2.w)) > THRESH) ? 8u : 0u;
        uint64_t w = pack16(nib);
        if ((lane & 15) == 0) buf[HALO + row][lane >> 4] = w;
    }

    // ---- phase 1b: halo rows (10 of them; slots 0..4 above, 5..9 below) ----
    {   // pass A: slots 0..7 (one wave each)
        const int slot = wave;
        const int gr   = (slot < 5) ? (r0 - HALO + slot) : (r0 + ROWS + (slot - 5));
        const int brow = (slot < 5) ? slot : (HALO + ROWS + (slot - 5));
        uint64_t w = pack16(mask_nib(X, bg, t, gr, col4));
        if ((lane & 15) == 0) buf[brow][lane >> 4] = w;
    }
    if (tid < 128) {  // pass B: slots 8..9 (waves 0..1)
        const int slot = 8 + wave;
        const int gr   = r0 + ROWS + (slot - 5);
        const int brow = HALO + ROWS + (slot - 5);
        uint64_t w = pack16(mask_nib(X, bg, t, gr, col4));
        if ((lane & 15) == 0) buf[brow][lane >> 4] = w;
    }
    __syncthreads();

    // ---- phase 2: 5 cross-dilation iterations, ONE wave, rows in lanes ----
    if (wave == 0) {
        uint64_t r_[4];
#pragma unroll
        for (int i = 0; i < 4; ++i) r_[i] = (lane < BROWS) ? buf[lane][i] : 0ULL;
#pragma unroll
        for (int it = 0; it < 5; ++it) {
            uint64_t nr[4];
#pragma unroll
            for (int i = 0; i < 4; ++i) {
                uint64_t c = r_[i];
                uint64_t l = (i > 0) ? r_[i - 1] : 0ULL;
                uint64_t rr = (i < 3) ? r_[i + 1] : 0ULL;
                uint64_t u = shfl64(c, lane - 1);       // lane0 wraps; masked below
                uint64_t d = shfl64(c, lane + 1);       // lane41 gets lane42 (=0)
                u = (lane == 0) ? 0ULL : u;
                nr[i] = c | (c << 1) | (l >> 63) | (c >> 1) | (rr << 63) | u | d;
            }
#pragma unroll
            for (int i = 0; i < 4; ++i) r_[i] = nr[i];
        }
        if (lane >= HALO && lane < HALO + ROWS) {
#pragma unroll
            for (int i = 0; i < 4; ++i) buf[lane][i] = r_[i];
        }
    }
    __syncthreads();

    // ---- phase 3: apply mask to register-held X, non-temporal store ----
#pragma unroll
    for (int k = 0; k < 4; ++k) {
        const int row = wave + 8 * k;
        const int gr  = r0 + row;
        uint64_t w = buf[HALO + row][col4 >> 4];
        uint32_t nb = (uint32_t)(w >> (4 * (col4 & 15))) & 0xFu;
        float m0 = (float)(nb & 1u);
        float m1 = (float)((nb >> 1) & 1u);
        float m2 = (float)((nb >> 2) & 1u);
        float m3 = (float)((nb >> 3) & 1u);
        size_t pix = (size_t)t * FRAME + (size_t)gr * WW + 4 * col4;
#pragma unroll
        for (int c = 0; c < 3; ++c) {
            float4 v = xv[k][c];
            nfloat4 nv = { v.x * m0, v.y * m1, v.z * m2, v.w * m3 };
            __builtin_nontemporal_store(nv, (nfloat4*)(out + (size_t)c * PLANE + pix));
        }
    }
}

extern "C" void kernel_launch(void* const* d_in, const int* in_sizes, int n_in,
                              void* d_out, int out_size, void* d_ws, size_t ws_size,
                              hipStream_t stream) {
    const float* X  = (const float*)d_in[0];
    const float* bg = (const float*)d_in[1];
    float* out = (float*)d_out;
    const int nblocks = TT * (HH / ROWS);   // 128 * 8 = 1024
    fused_kernel<<<nblocks, 512, 0, stream>>>(X, bg, out);
}